// Round 1
// baseline (189.358 us; speedup 1.0000x reference)
//
#include <hip/hip_runtime.h>

#define B_ 64
#define NB_ 8
#define Q_ 32
#define T_ 256
#define D_ 256
#define NBINS 11

// ---------------------------------------------------------------------------
// Kernel 1: inverse L2 norms for can rows (B*T) and hq rows (B*NB*Q).
// One wave per 256-float row: float4 load, shuffle reduce.
// ---------------------------------------------------------------------------
__global__ __launch_bounds__(256) void norms_kernel(
    const float* __restrict__ can, const float* __restrict__ hq,
    float* __restrict__ inv_can, float* __restrict__ inv_hq) {
  int gwave = (blockIdx.x * 256 + threadIdx.x) >> 6;
  int lane = threadIdx.x & 63;
  const float* src;
  float* dst;
  if (gwave < B_ * T_) {
    src = can + (size_t)gwave * D_;
    dst = inv_can + gwave;
  } else {
    int r = gwave - B_ * T_;
    src = hq + (size_t)r * D_;
    dst = inv_hq + r;
  }
  float4 v = reinterpret_cast<const float4*>(src)[lane];
  float s = v.x * v.x + v.y * v.y + v.z * v.z + v.w * v.w;
#pragma unroll
  for (int off = 32; off > 0; off >>= 1) s += __shfl_down(s, off);
  if (lane == 0) *dst = 1.0f / fmaxf(sqrtf(s), 1e-10f);
}

// ---------------------------------------------------------------------------
// Kernel 2: per (b,n) block — cosine matrix (32q x 256t), Gaussian bins,
// masked t-sum, log-pool, q-sum -> pooled[bid][11] via global atomics.
// LDS: hq tile 32x256 + can chunk 32x256, XOR-swizzled float4 layout
// (slot = row*64 + (chunk ^ (row&7))) -> 2-way bank aliasing only (free).
// Exactly 64 KB static LDS.
// ---------------------------------------------------------------------------
__global__ __launch_bounds__(256) void pool_kernel(
    const float* __restrict__ hq, const float* __restrict__ can,
    const float* __restrict__ word_atten, const float* __restrict__ mask_hq,
    const float* __restrict__ mask_can, const float* __restrict__ inv_hq,
    const float* __restrict__ inv_can, float* __restrict__ pooled) {
  __shared__ float4 hq_sm[Q_ * 64];    // 32 rows x 64 float4 = 32 KB
  __shared__ float4 can_sm[32 * 64];   // 32 rows x 64 float4 = 32 KB

  const float mus[NBINS] = {1.0f, 0.9f, 0.7f, 0.5f, 0.3f, 0.1f,
                            -0.1f, -0.3f, -0.5f, -0.7f, -0.9f};
  const float is2[NBINS] = {5.0e5f, 50.f, 50.f, 50.f, 50.f, 50.f,
                            50.f, 50.f, 50.f, 50.f, 50.f};

  int bid = blockIdx.x;  // b*8 + n, 0..511
  int b = bid >> 3;
  int tid = threadIdx.x;
  int wv = tid >> 6, lane = tid & 63;

  // stage hq tile (normalized)
  const float* hq_base = hq + (size_t)bid * (Q_ * D_);
  const float* invhq_b = inv_hq + bid * Q_;
#pragma unroll
  for (int i = 0; i < 8; i++) {
    int row = wv * 8 + i;
    float4 v = reinterpret_cast<const float4*>(hq_base + row * D_)[lane];
    float s = invhq_b[row];
    v.x *= s; v.y *= s; v.z *= s; v.w *= s;
    hq_sm[row * 64 + (lane ^ (row & 7))] = v;
  }

  int qp = tid >> 4;  // 0..15 -> q rows {qp, qp+16}
  int tp = tid & 15;  // 0..15 -> t cols {tp, tp+16} within chunk

  float binacc[2][NBINS];
#pragma unroll
  for (int qi = 0; qi < 2; qi++)
#pragma unroll
    for (int j = 0; j < NBINS; j++) binacc[qi][j] = 0.0f;

  const float* can_base = can + (size_t)b * (T_ * D_);
  const float* invcan_b = inv_can + b * T_;
  const float* maskcan_b = mask_can + b * T_;

  int hx = qp & 7;  // swizzle key, shared by rows qp and qp+16
  int cx = tp & 7;  // shared by rows tp and tp+16
  const float4* h0 = &hq_sm[qp * 64];
  const float4* h1 = &hq_sm[(qp + 16) * 64];
  const float4* c0 = &can_sm[tp * 64];
  const float4* c1 = &can_sm[(tp + 16) * 64];

  for (int ch = 0; ch < 8; ch++) {
    __syncthreads();  // previous chunk fully consumed
#pragma unroll
    for (int i = 0; i < 8; i++) {
      int r = wv * 8 + i;
      int t = ch * 32 + r;
      float4 v = reinterpret_cast<const float4*>(can_base + t * D_)[lane];
      float s = invcan_b[t];
      v.x *= s; v.y *= s; v.z *= s; v.w *= s;
      can_sm[r * 64 + (lane ^ (r & 7))] = v;
    }
    __syncthreads();

    float4 a00 = {0, 0, 0, 0}, a01 = {0, 0, 0, 0};
    float4 a10 = {0, 0, 0, 0}, a11 = {0, 0, 0, 0};
#pragma unroll 8
    for (int d = 0; d < 64; d++) {
      float4 x0 = h0[d ^ hx];
      float4 x1 = h1[d ^ hx];
      float4 y0 = c0[d ^ cx];
      float4 y1 = c1[d ^ cx];
      a00.x += x0.x * y0.x; a00.y += x0.y * y0.y; a00.z += x0.z * y0.z; a00.w += x0.w * y0.w;
      a01.x += x0.x * y1.x; a01.y += x0.y * y1.y; a01.z += x0.z * y1.z; a01.w += x0.w * y1.w;
      a10.x += x1.x * y0.x; a10.y += x1.y * y0.y; a10.z += x1.z * y0.z; a10.w += x1.w * y0.w;
      a11.x += x1.x * y1.x; a11.y += x1.y * y1.y; a11.z += x1.z * y1.z; a11.w += x1.w * y1.w;
    }
    float m00 = a00.x + a00.y + a00.z + a00.w;
    float m01 = a01.x + a01.y + a01.z + a01.w;
    float m10 = a10.x + a10.y + a10.z + a10.w;
    float m11 = a11.x + a11.y + a11.z + a11.w;

    float mk0 = maskcan_b[ch * 32 + tp];
    float mk1 = maskcan_b[ch * 32 + tp + 16];
#pragma unroll
    for (int j = 0; j < NBINS; j++) {
      float dd;
      dd = m00 - mus[j]; binacc[0][j] += mk0 * __expf(-dd * dd * is2[j]);
      dd = m01 - mus[j]; binacc[0][j] += mk1 * __expf(-dd * dd * is2[j]);
      dd = m10 - mus[j]; binacc[1][j] += mk0 * __expf(-dd * dd * is2[j]);
      dd = m11 - mus[j]; binacc[1][j] += mk1 * __expf(-dd * dd * is2[j]);
    }
  }

  // reduce bin sums across the 16 threads (tp) sharing each q pair
#pragma unroll
  for (int j = 0; j < NBINS; j++) {
    float v0 = binacc[0][j], v1 = binacc[1][j];
#pragma unroll
    for (int off = 8; off > 0; off >>= 1) {
      v0 += __shfl_xor(v0, off);
      v1 += __shfl_xor(v1, off);
    }
    binacc[0][j] = v0;
    binacc[1][j] = v1;
  }
  if (tp == 0) {
#pragma unroll
    for (int qi = 0; qi < 2; qi++) {
      int q = qp + qi * 16;
      float wa = word_atten[bid * Q_ + q] * mask_hq[bid * Q_ + q];
#pragma unroll
      for (int j = 0; j < NBINS; j++) {
        float lp = logf(fmaxf(binacc[qi][j], 1e-10f)) * 0.01f * wa;
        atomicAdd(&pooled[bid * NBINS + j], lp);
      }
    }
  }
}

// ---------------------------------------------------------------------------
// Kernel 3: per-b epilogue — W_att projection, masked softmax over NB,
// tanh(pooled@W_dense + b) weighted sum.
// ---------------------------------------------------------------------------
__global__ __launch_bounds__(256) void final_kernel(
    const float* __restrict__ rep, const float* __restrict__ rep_cur,
    const float* __restrict__ mask_session, const float* __restrict__ W_dense,
    const float* __restrict__ b_dense, const float* __restrict__ W_att,
    const float* __restrict__ b_att, const float* __restrict__ pooled,
    float* __restrict__ out) {
  __shared__ float qproj[D_];
  __shared__ float scores_sm[NB_];
  int b = blockIdx.x, tid = threadIdx.x;

  const float* rc = rep_cur + b * D_;
  float acc = b_att[tid];
  for (int k = 0; k < D_; k++) acc += rc[k] * W_att[k * D_ + tid];
  qproj[tid] = acc;
  __syncthreads();

  int wv = tid >> 6, lane = tid & 63;
  for (int nn = wv; nn < NB_; nn += 4) {
    const float* rp = rep + ((size_t)b * NB_ + nn) * D_;
    float4 r4 = reinterpret_cast<const float4*>(rp)[lane];
    float4 q4 = *reinterpret_cast<float4*>(&qproj[lane * 4]);
    float s = r4.x * q4.x + r4.y * q4.y + r4.z * q4.z + r4.w * q4.w;
#pragma unroll
    for (int off = 32; off > 0; off >>= 1) s += __shfl_down(s, off);
    if (lane == 0) scores_sm[nn] = s * 0.0625f;  // 1/sqrt(256)
  }
  __syncthreads();

  if (tid == 0) {
    float sc[NB_];
    float mx = -1e30f;
    for (int nn = 0; nn < NB_; nn++) {
      float s = (mask_session[b * NB_ + nn] > 0.f) ? scores_sm[nn] : -1e9f;
      sc[nn] = s;
      mx = fmaxf(mx, s);
    }
    float den = 0.f;
    for (int nn = 0; nn < NB_; nn++) {
      sc[nn] = __expf(sc[nn] - mx);
      den += sc[nn];
    }
    float res = 0.f;
    for (int nn = 0; nn < NB_; nn++) {
      float ms = mask_session[b * NB_ + nn];
      float pw = b_dense[0];
      for (int j = 0; j < NBINS; j++)
        pw += pooled[(b * NB_ + nn) * NBINS + j] * ms * W_dense[j];
      res += tanhf(pw) * (sc[nn] / den);
    }
    out[b] = res;
  }
}

// ---------------------------------------------------------------------------
// ws layout (floats): [0,16384) inv_can | [16384,32768) inv_hq |
//                     [32768, 32768+512*11) pooled
// required ws >= 153.6 KB
// ---------------------------------------------------------------------------
extern "C" void kernel_launch(void* const* d_in, const int* in_sizes, int n_in,
                              void* d_out, int out_size, void* d_ws,
                              size_t ws_size, hipStream_t stream) {
  const float* word_atten = (const float*)d_in[0];
  const float* hq = (const float*)d_in[1];
  const float* can = (const float*)d_in[2];
  const float* rep = (const float*)d_in[3];
  const float* rep_cur = (const float*)d_in[4];
  const float* mask_hq = (const float*)d_in[5];
  const float* mask_can = (const float*)d_in[6];
  const float* mask_session = (const float*)d_in[7];
  const float* W_dense = (const float*)d_in[8];
  const float* b_dense = (const float*)d_in[9];
  const float* W_att = (const float*)d_in[10];
  const float* b_att = (const float*)d_in[11];
  float* out = (float*)d_out;

  float* ws = (float*)d_ws;
  float* inv_can = ws;
  float* inv_hq = ws + 16384;
  float* pooled = ws + 32768;

  // zero the pooled accumulator (ws is poisoned before every launch)
  hipMemsetAsync(pooled, 0, (size_t)(B_ * NB_ * NBINS) * sizeof(float), stream);

  // 32768 rows total, 4 waves/block
  hipLaunchKernelGGL(norms_kernel, dim3(8192), dim3(256), 0, stream, can, hq,
                     inv_can, inv_hq);
  hipLaunchKernelGGL(pool_kernel, dim3(B_ * NB_), dim3(256), 0, stream, hq, can,
                     word_atten, mask_hq, mask_can, inv_hq, inv_can, pooled);
  hipLaunchKernelGGL(final_kernel, dim3(B_), dim3(256), 0, stream, rep, rep_cur,
                     mask_session, W_dense, b_dense, W_att, b_att, pooled, out);
}

// Round 4
// 147.856 us; speedup vs baseline: 1.2807x; 1.2807x over previous
//
#include <hip/hip_runtime.h>

#define B_ 64
#define NB_ 8
#define Q_ 32
#define T_ 256
#define D_ 256
#define NBINS 11

typedef __attribute__((ext_vector_type(8))) short bf16x8;
typedef __attribute__((ext_vector_type(4))) float f32x4;
typedef unsigned short ushort_t;
typedef unsigned int uint_t;

__device__ inline ushort_t bf16_rnd(float f) {
  uint_t u = __float_as_uint(f);
  return (ushort_t)((u + 0x8000u) >> 16);
}
__device__ inline uint_t pack2(ushort_t a, ushort_t b) {
  return (uint_t)a | ((uint_t)b << 16);
}

// ---------------------------------------------------------------------------
// pool_kernel: one block per (b,nb).
// C[32q x 256t] = hq_n . can_n^T in ~fp32 precision via split-bf16 3-MFMA:
//   x = hi + lo (hi = bf16(x), lo = bf16(x - hi));  m = hi*hi + hi*lo + lo*hi
// A (hq rows) kept entirely in registers; can staged per 32-row chunk as
// hi/lo bf16 LDS (33.8 KB). Row norms computed inline.
// Gaussian bin pass on C fragments -> block reduction -> pooled[outb][11].
//
// R3 bugfix: the lp_sm stage covers Q_*NBINS = 352 work items with 256
// threads -> MUST be a strided loop, not `if (tid < 352)`. (R2/R3 failures
// were q-rows 23..31 reading stale LDS-overlay garbage.)
// ---------------------------------------------------------------------------
__global__ __launch_bounds__(256) void pool_kernel(
    const float* __restrict__ hq, const float* __restrict__ can,
    const float* __restrict__ word_atten, const float* __restrict__ mask_hq,
    const float* __restrict__ mask_can, float* __restrict__ pooled) {
  __shared__ __align__(16) ushort_t can_hi[32 * 264];  // 16896 B
  __shared__ __align__(16) ushort_t can_lo[32 * 264];  // 16896 B
  // epilogue overlays (after final __syncthreads, can_* no longer read):
  float* partial = (float*)can_hi;        // [4 waves][16 rows][11] = 704 f
  float* lp_sm = ((float*)can_hi) + 704;  // [32 q][11] = 352 f

  const float mus[NBINS] = {1.0f, 0.9f, 0.7f, 0.5f, 0.3f, 0.1f,
                            -0.1f, -0.3f, -0.5f, -0.7f, -0.9f};
  const float is2[NBINS] = {5.0e5f, 50.f, 50.f, 50.f, 50.f, 50.f,
                            50.f, 50.f, 50.f, 50.f, 50.f};

  int b = blockIdx.x & 63;   // XCD-swizzle: all 8 nb-blocks of one b share L2
  int nb = blockIdx.x >> 6;
  int outb = b * NB_ + nb;
  int tid = threadIdx.x;
  int wv = tid >> 6, lane = tid & 63;
  int lq = lane & 15, lk = lane >> 4;
  int mtile = wv >> 1, ntile = wv & 1;

  const float* hq_base = hq + (size_t)outb * (Q_ * D_);
  const float* can_base = can + (size_t)b * (T_ * D_);
  const float* maskcan_b = mask_can + b * T_;

  // ---- A fragments in registers, hi/lo split, inline row norm ----
  // A[m=lq][k]: lane holds k = kk*32 + lk*8 + j  (kk=0..8, j=0..8)
  const float* arow = hq_base + (size_t)(mtile * 16 + lq) * D_;
  float sumsq = 0.f;
#pragma unroll
  for (int kk = 0; kk < 8; kk++) {
    const float* p = arow + kk * 32 + lk * 8;
    float4 x = reinterpret_cast<const float4*>(p)[0];
    float4 y = reinterpret_cast<const float4*>(p)[1];
    sumsq += x.x * x.x + x.y * x.y + x.z * x.z + x.w * x.w +
             y.x * y.x + y.y * y.y + y.z * y.z + y.w * y.w;
  }
  // lanes sharing lq differ in lk -> xor 16, 32 completes the 256-elem row
  sumsq += __shfl_xor(sumsq, 16);
  sumsq += __shfl_xor(sumsq, 32);
  float ainv = 1.0f / fmaxf(sqrtf(sumsq), 1e-10f);

  bf16x8 a_hi[8], a_lo[8];
#pragma unroll
  for (int kk = 0; kk < 8; kk++) {
    const float* p = arow + kk * 32 + lk * 8;
    float4 x = reinterpret_cast<const float4*>(p)[0];
    float4 y = reinterpret_cast<const float4*>(p)[1];
    float v[8] = {x.x, x.y, x.z, x.w, y.x, y.y, y.z, y.w};
    union { bf16x8 v8; ushort_t u[8]; } H, L;
#pragma unroll
    for (int j = 0; j < 8; j++) {
      float s = v[j] * ainv;
      ushort_t h = bf16_rnd(s);
      float hf = __uint_as_float(((uint_t)h) << 16);
      H.u[j] = h;
      L.u[j] = bf16_rnd(s - hf);
    }
    a_hi[kk] = H.v8;
    a_lo[kk] = L.v8;
  }

  float binacc[4][NBINS];
#pragma unroll
  for (int r = 0; r < 4; r++)
#pragma unroll
    for (int j = 0; j < NBINS; j++) binacc[r][j] = 0.0f;

  for (int ch = 0; ch < 8; ch++) {
    __syncthreads();  // previous chunk fully consumed
    // ---- stage can chunk: 32 rows, inline norm, split hi/lo ----
#pragma unroll
    for (int it = 0; it < 4; it++) {
      int flat = it * 2048 + tid * 8;
      int row = flat >> 8, col = flat & 255;
      int trow = ch * 32 + row;
      const float* src = can_base + (size_t)trow * D_ + col;
      float4 x = reinterpret_cast<const float4*>(src)[0];
      float4 y = reinterpret_cast<const float4*>(src)[1];
      float s = x.x * x.x + x.y * x.y + x.z * x.z + x.w * x.w +
                y.x * y.x + y.y * y.y + y.z * y.z + y.w * y.w;
      // 32 threads (one 32-lane group) share a row
      s += __shfl_xor(s, 1);
      s += __shfl_xor(s, 2);
      s += __shfl_xor(s, 4);
      s += __shfl_xor(s, 8);
      s += __shfl_xor(s, 16);
      float inv = 1.0f / fmaxf(sqrtf(s), 1e-10f);
      float v[8] = {x.x, x.y, x.z, x.w, y.x, y.y, y.z, y.w};
      ushort_t h[8], l[8];
#pragma unroll
      for (int j = 0; j < 8; j++) {
        float sv = v[j] * inv;
        h[j] = bf16_rnd(sv);
        float hf = __uint_as_float(((uint_t)h[j]) << 16);
        l[j] = bf16_rnd(sv - hf);
      }
      uint4 ph = {pack2(h[0], h[1]), pack2(h[2], h[3]),
                  pack2(h[4], h[5]), pack2(h[6], h[7])};
      uint4 pl = {pack2(l[0], l[1]), pack2(l[2], l[3]),
                  pack2(l[4], l[5]), pack2(l[6], l[7])};
      *reinterpret_cast<uint4*>(&can_hi[row * 264 + col]) = ph;
      *reinterpret_cast<uint4*>(&can_lo[row * 264 + col]) = pl;
    }
    __syncthreads();

    // ---- 3-MFMA split K-loop (one 16x16 tile per wave) ----
    f32x4 acc = {0.f, 0.f, 0.f, 0.f};
    const ushort_t* Bhi = &can_hi[(ntile * 16 + lq) * 264];
    const ushort_t* Blo = &can_lo[(ntile * 16 + lq) * 264];
#pragma unroll
    for (int kk = 0; kk < 8; kk++) {
      int off = kk * 32 + lk * 8;
      bf16x8 bh = *reinterpret_cast<const bf16x8*>(Bhi + off);
      bf16x8 bl = *reinterpret_cast<const bf16x8*>(Blo + off);
      acc = __builtin_amdgcn_mfma_f32_16x16x32_bf16(a_hi[kk], bh, acc, 0, 0, 0);
      acc = __builtin_amdgcn_mfma_f32_16x16x32_bf16(a_lo[kk], bh, acc, 0, 0, 0);
      acc = __builtin_amdgcn_mfma_f32_16x16x32_bf16(a_hi[kk], bl, acc, 0, 0, 0);
    }

    // ---- Gaussian bin pass on C fragment ----
    // C/D: col(t) = lane&15, row(q) = (lane>>4)*4 + reg
    int t0 = ch * 32 + ntile * 16 + lq;
    float mk = maskcan_b[t0];
#pragma unroll
    for (int r = 0; r < 4; r++) {
      float v0 = acc[r];
#pragma unroll
      for (int j = 0; j < NBINS; j++) {
        float d0 = v0 - mus[j];
        binacc[r][j] += mk * __expf(-d0 * d0 * is2[j]);
      }
    }
  }

  __syncthreads();  // can_hi/lo dead; overlay reductions

  // reduce over the 16 t-cols (lq) held by this wave
#pragma unroll
  for (int r = 0; r < 4; r++)
#pragma unroll
    for (int j = 0; j < NBINS; j++) {
      float v = binacc[r][j];
      v += __shfl_xor(v, 1);
      v += __shfl_xor(v, 2);
      v += __shfl_xor(v, 4);
      v += __shfl_xor(v, 8);
      binacc[r][j] = v;
    }
  if (lq == 0) {
#pragma unroll
    for (int r = 0; r < 4; r++)
#pragma unroll
      for (int j = 0; j < NBINS; j++)
        partial[(wv * 16 + lk * 4 + r) * NBINS + j] = binacc[r][j];
  }
  __syncthreads();

  // combine wave pairs (ntile 0/1 halves), log-pool * word_atten * mask_hq.
  // STRIDED: 352 items > 256 threads (the R2/R3 bug).
  for (int idx = tid; idx < Q_ * NBINS; idx += 256) {
    int q = idx / NBINS;
    int j = idx - q * NBINS;
    int mt = q >> 4, lr = q & 15;
    float sum = partial[((2 * mt) * 16 + lr) * NBINS + j] +
                partial[((2 * mt + 1) * 16 + lr) * NBINS + j];
    float wa = word_atten[outb * Q_ + q] * mask_hq[outb * Q_ + q];
    lp_sm[q * NBINS + j] = logf(fmaxf(sum, 1e-10f)) * 0.01f * wa;
  }
  __syncthreads();

  if (tid < NBINS) {
    float acc2 = 0.f;
#pragma unroll
    for (int q = 0; q < Q_; q++) acc2 += lp_sm[q * NBINS + tid];
    pooled[outb * NBINS + tid] = acc2;
  }
}

// ---------------------------------------------------------------------------
// final_kernel: per-b epilogue — W_att projection, masked softmax over NB,
// tanh(pooled@W_dense + b) weighted sum.
// ---------------------------------------------------------------------------
__global__ __launch_bounds__(256) void final_kernel(
    const float* __restrict__ rep, const float* __restrict__ rep_cur,
    const float* __restrict__ mask_session, const float* __restrict__ W_dense,
    const float* __restrict__ b_dense, const float* __restrict__ W_att,
    const float* __restrict__ b_att, const float* __restrict__ pooled,
    float* __restrict__ out) {
  __shared__ float qproj[D_];
  __shared__ float scores_sm[NB_];
  int b = blockIdx.x, tid = threadIdx.x;

  const float* rc = rep_cur + b * D_;
  float acc = b_att[tid];
  for (int k = 0; k < D_; k++) acc += rc[k] * W_att[k * D_ + tid];
  qproj[tid] = acc;
  __syncthreads();

  int wv = tid >> 6, lane = tid & 63;
  for (int nn = wv; nn < NB_; nn += 4) {
    const float* rp = rep + ((size_t)b * NB_ + nn) * D_;
    float4 r4 = reinterpret_cast<const float4*>(rp)[lane];
    float4 q4 = *reinterpret_cast<float4*>(&qproj[lane * 4]);
    float s = r4.x * q4.x + r4.y * q4.y + r4.z * q4.z + r4.w * q4.w;
#pragma unroll
    for (int off = 32; off > 0; off >>= 1) s += __shfl_down(s, off);
    if (lane == 0) scores_sm[nn] = s * 0.0625f;  // 1/sqrt(256)
  }
  __syncthreads();

  if (tid == 0) {
    float sc[NB_];
    float mx = -1e30f;
    for (int nn = 0; nn < NB_; nn++) {
      float s = (mask_session[b * NB_ + nn] > 0.f) ? scores_sm[nn] : -1e9f;
      sc[nn] = s;
      mx = fmaxf(mx, s);
    }
    float den = 0.f;
    for (int nn = 0; nn < NB_; nn++) {
      sc[nn] = __expf(sc[nn] - mx);
      den += sc[nn];
    }
    float res = 0.f;
    for (int nn = 0; nn < NB_; nn++) {
      float ms = mask_session[b * NB_ + nn];
      float pw = b_dense[0];
      for (int j = 0; j < NBINS; j++)
        pw += pooled[(b * NB_ + nn) * NBINS + j] * ms * W_dense[j];
      res += tanhf(pw) * (sc[nn] / den);
    }
    out[b] = res;
  }
}

// ---------------------------------------------------------------------------
// ws layout (floats): [0, 512*11) pooled. Written once per pool block.
// ---------------------------------------------------------------------------
extern "C" void kernel_launch(void* const* d_in, const int* in_sizes, int n_in,
                              void* d_out, int out_size, void* d_ws,
                              size_t ws_size, hipStream_t stream) {
  const float* word_atten = (const float*)d_in[0];
  const float* hq = (const float*)d_in[1];
  const float* can = (const float*)d_in[2];
  const float* rep = (const float*)d_in[3];
  const float* rep_cur = (const float*)d_in[4];
  const float* mask_hq = (const float*)d_in[5];
  const float* mask_can = (const float*)d_in[6];
  const float* mask_session = (const float*)d_in[7];
  const float* W_dense = (const float*)d_in[8];
  const float* b_dense = (const float*)d_in[9];
  const float* W_att = (const float*)d_in[10];
  const float* b_att = (const float*)d_in[11];
  float* out = (float*)d_out;

  float* pooled = (float*)d_ws;

  hipLaunchKernelGGL(pool_kernel, dim3(B_ * NB_), dim3(256), 0, stream, hq, can,
                     word_atten, mask_hq, mask_can, pooled);
  hipLaunchKernelGGL(final_kernel, dim3(B_), dim3(256), 0, stream, rep, rep_cur,
                     mask_session, W_dense, b_dense, W_att, b_att, pooled, out);
}